// Round 5
// baseline (326.291 us; speedup 1.0000x reference)
//
#include <hip/hip_runtime.h>
#include <stdint.h>

typedef unsigned short u16;
typedef int i32x4 __attribute__((ext_vector_type(4)));
typedef unsigned int u32x4 __attribute__((ext_vector_type(4)));
typedef unsigned int u32x2 __attribute__((ext_vector_type(2)));

#define DDIM 1024
#define FDIM 2048
#define NEXP 8
#define RT_TILES 72      /* routed row tiles: 9216/128 */
#define SHOFF 9216       /* start row of shared-expert segment */
#define RCAP 13312       /* 9216 routed (padded) + 4096 shared rows */
#define NRT 104          /* RCAP/128 row tiles */
#define UPROWS 16384     /* NEXP*FDIM routed up rows */
#define DNROWS 8192      /* NEXP*DDIM routed down rows */
#define UPTOT (UPROWS + FDIM)    /* 18432 up rows incl. shared */
#define DNTOT (DNROWS + DDIM)    /* 9216 down rows incl. shared */
#define UPT2 (UPTOT / 2)         /* 9216 two-row up tasks (4 KB each) */
#define WQ_NT (UPT2 + DNTOT)     /* 18432 tasks total */
#define WQ_NW 4096               /* persistent waves: 1024 blocks x 4 waves */

// meta: [0..7] counts, [8..15] base[e], [16] total_padded, [30] dtype flag (1=fp32 inputs)

__device__ inline float bf2f(u16 u) {
    union { unsigned int i; float f; } v; v.i = ((unsigned int)u) << 16; return v.f;
}
__device__ inline u16 f2bf(float f) {
    union { float f; unsigned int i; } v; v.f = f;
    unsigned int lsb = (v.i >> 16) & 1u;
    return (u16)((v.i + 0x7fffu + lsb) >> 16);
}
__device__ inline int q8(float v, float inv) {
    int x = (int)rintf(v * inv);
    return x < -127 ? -127 : (x > 127 ? 127 : x);
}
__device__ inline unsigned pack4(float a, float b, float c, float d, float inv) {
    return (unsigned)(q8(a, inv) & 255) | ((unsigned)(q8(b, inv) & 255) << 8) |
           ((unsigned)(q8(c, inv) & 255) << 16) | ((unsigned)(q8(d, inv) & 255) << 24);
}

// ---- non-temporal (L1-bypass / streaming) access helpers ----
__device__ inline u32x4 ntld16(const char* p) {
    return __builtin_nontemporal_load((const u32x4*)p);
}
__device__ inline u32x2 ntld8(const char* p) {
    return __builtin_nontemporal_load((const u32x2*)p);
}
__device__ inline void ntst8(char* p, u32x2 v) {
    __builtin_nontemporal_store(v, (u32x2*)p);
}

__device__ inline float absmax8(u32x4 p) {
    union { u32x4 v; u16 h[8]; } u; u.v = p;
    float m = fabsf(bf2f(u.h[0]));
    #pragma unroll
    for (int d = 1; d < 8; d++) m = fmaxf(m, fabsf(bf2f(u.h[d])));
    return m;
}
__device__ inline void store8(char* dst, u32x4 p, float inv) {
    union { u32x4 v; u16 h[8]; } u; u.v = p;
    u32x2 o;
    o[0] = pack4(bf2f(u.h[0]), bf2f(u.h[1]), bf2f(u.h[2]), bf2f(u.h[3]), inv);
    o[1] = pack4(bf2f(u.h[4]), bf2f(u.h[5]), bf2f(u.h[6]), bf2f(u.h[7]), inv);
    ntst8(dst, o);
}
__device__ inline float wredmax(float m) {
    #pragma unroll
    for (int off = 32; off > 0; off >>= 1) m = fmaxf(m, __shfl_xor(m, off, 64));
    return m;
}

typedef const __attribute__((address_space(1))) void gas_void;
typedef __attribute__((address_space(3))) void las_void;
#define GLL16(g, l) __builtin_amdgcn_global_load_lds((gas_void*)(g), (las_void*)(l), 16, 0, 0)

// ---- One-shot dtype detect over first 1024 halfwords of x -> meta[30] ----
__global__ __launch_bounds__(256) void detect_kernel(
    const u16* __restrict__ x, int* __restrict__ meta)
{
    __shared__ int scnt;
    if (threadIdx.x == 0) scnt = 0;
    __syncthreads();
    int bad = 0;
    #pragma unroll
    for (int i = 0; i < 4; i++) {
        u16 v = x[threadIdx.x * 4 + i];
        if (((v >> 7) & 0xFF) >= 0x8F) bad++;
    }
    if (bad) atomicAdd(&scnt, bad);
    __syncthreads();
    if (threadIdx.x == 0) meta[30] = (scnt > 32) ? 1 : 0;
}

// ======== Router: 16 tokens/block, fp32 logits -> top2 (no atomics) ========
__global__ __launch_bounds__(256) void router_kernel(
    const void* __restrict__ x_, const void* __restrict__ rw_, const void* __restrict__ rb_,
    float* __restrict__ top_w, int* __restrict__ top_idx, const int* __restrict__ meta)
{
    __shared__ char smem[32768];
    const int tid = threadIdx.x;
    const int wave = tid >> 6, lane = tid & 63;
    const int flag = meta[30];

    float* rws = (float*)smem;
    if (!flag) {
        const ushort4* rwv = (const ushort4*)rw_;
        #pragma unroll
        for (int i = 0; i < 8; i++) {
            int idx = tid + i * 256;
            ushort4 h = rwv[idx];
            rws[idx * 4 + 0] = bf2f(h.x); rws[idx * 4 + 1] = bf2f(h.y);
            rws[idx * 4 + 2] = bf2f(h.z); rws[idx * 4 + 3] = bf2f(h.w);
        }
    } else {
        const float4* rwv = (const float4*)rw_;
        #pragma unroll
        for (int i = 0; i < 8; i++) {
            int idx = tid + i * 256;
            float4 f = rwv[idx];
            rws[idx * 4 + 0] = f.x; rws[idx * 4 + 1] = f.y;
            rws[idx * 4 + 2] = f.z; rws[idx * 4 + 3] = f.w;
        }
    }
    __syncthreads();

    for (int sub = 0; sub < 4; sub++) {
        const int t = blockIdx.x * 16 + wave * 4 + sub;
        float xv[16];
        if (!flag) {
            const u16* xr = (const u16*)x_ + (size_t)t * DDIM + lane * 16;
            uint4 p0 = *(const uint4*)(xr);
            uint4 p1 = *(const uint4*)(xr + 8);
            #pragma unroll
            for (int d = 0; d < 8; d++) xv[d]     = bf2f(((const u16*)&p0)[d]);
            #pragma unroll
            for (int d = 0; d < 8; d++) xv[d + 8] = bf2f(((const u16*)&p1)[d]);
        } else {
            const float4* xr = (const float4*)((const float*)x_ + (size_t)t * DDIM + lane * 16);
            #pragma unroll
            for (int c = 0; c < 4; c++) {
                float4 f = xr[c];
                xv[c * 4 + 0] = f.x; xv[c * 4 + 1] = f.y;
                xv[c * 4 + 2] = f.z; xv[c * 4 + 3] = f.w;
            }
        }
        float acc[NEXP];
        #pragma unroll
        for (int e = 0; e < NEXP; e++) {
            const float* wr = &rws[e * DDIM + lane * 16];
            float s = 0.f;
            #pragma unroll
            for (int d = 0; d < 16; d++) s += xv[d] * wr[d];
            acc[e] = s;
        }
        #pragma unroll
        for (int e = 0; e < NEXP; e++) {
            #pragma unroll
            for (int off = 32; off > 0; off >>= 1)
                acc[e] += __shfl_xor(acc[e], off, 64);
        }
        if (lane == 0) {
            float lg[NEXP];
            #pragma unroll
            for (int e = 0; e < NEXP; e++) {
                float b = flag ? ((const float*)rb_)[e] : bf2f(((const u16*)rb_)[e]);
                lg[e] = acc[e] + b;
            }
            int i0 = 0;
            #pragma unroll
            for (int e = 1; e < NEXP; e++) if (lg[e] > lg[i0]) i0 = e;
            int i1 = (i0 == 0) ? 1 : 0;
            #pragma unroll
            for (int e = 0; e < NEXP; e++) if (e != i0 && lg[e] > lg[i1]) i1 = e;
            float e1 = __expf(lg[i1] - lg[i0]);
            float w0 = 1.f / (1.f + e1);
            float w1 = e1 / (1.f + e1);
            top_w[2 * t] = w0;  top_w[2 * t + 1] = w1;
            top_idx[2 * t] = i0; top_idx[2 * t + 1] = i1;
        }
    }
}

// ======== Weight quantize: PERSISTENT, nt streaming, 4 KB tasks ========
// 4096 waves; task t<UPT2: 2 up rows (2x2KB bf16); else: 1 down row (4KB).
// All loads/stores non-temporal: weights are stream-once, L1 caching is waste.

__device__ inline const char* wq_src(int t, const char* wup, const char* swup,
                                     const char* wdn, const char* swdn) {
    if (t < UPT2) {
        const int R0 = t * 2;
        return (R0 < UPROWS) ? wup + (size_t)R0 * 2048
                             : swup + (size_t)(R0 - UPROWS) * 2048;
    }
    const int R = t - UPT2;
    return (R < DNROWS) ? wdn + (size_t)R * 4096
                        : swdn + (size_t)(R - DNROWS) * 4096;
}

// fp32 fallback: two-pass global read (2nd pass L2-hits), unpipelined cold path.
template<int NC>
__device__ inline void wq_f32(const char* __restrict__ src, char* __restrict__ dst,
                              float* __restrict__ sout, int R, int lane) {
    float m = 0.f;
    #pragma unroll
    for (int c = 0; c < NC; c++) {
        float4 f = *(const float4*)(src + (size_t)c * 1024 + lane * 16);
        m = fmaxf(m, fmaxf(fmaxf(fabsf(f.x), fabsf(f.y)),
                           fmaxf(fabsf(f.z), fabsf(f.w))));
    }
    m = wredmax(m);
    m = fmaxf(m, 1e-12f);
    if (lane == 0) sout[R] = m / 127.f;
    const float inv = 127.f / m;
    #pragma unroll
    for (int c = 0; c < NC; c++) {
        float4 f = *(const float4*)(src + (size_t)c * 1024 + lane * 16);
        *(unsigned*)(dst + (size_t)c * 256 + lane * 4) = pack4(f.x, f.y, f.z, f.w, inv);
    }
}

__global__ __launch_bounds__(256) void wquant_kernel(
    const void* __restrict__ w_up, const void* __restrict__ w_down,
    const void* __restrict__ sw_up, const void* __restrict__ sw_down,
    char* __restrict__ qup, char* __restrict__ qdn,
    float* __restrict__ su, float* __restrict__ sd, const int* __restrict__ meta)
{
    const int gwid = (blockIdx.x * blockDim.x + threadIdx.x) >> 6;  // 0..WQ_NW-1
    const int lane = threadIdx.x & 63;
    const int flag = meta[30];

    if (flag) {   // fp32 inputs: simple grid-stride (cold path)
        for (int t = gwid; t < WQ_NT; t += WQ_NW) {
            if (t < UPT2) {
                const int R0 = t * 2;
                const char* src = (R0 < UPROWS)
                    ? (const char*)w_up + (size_t)R0 * 4096
                    : (const char*)sw_up + (size_t)(R0 - UPROWS) * 4096;
                wq_f32<4>(src,        qup + (size_t)R0 * 1024,       su, R0,     lane);
                wq_f32<4>(src + 4096, qup + (size_t)(R0 + 1) * 1024, su, R0 + 1, lane);
            } else {
                const int R = t - UPT2;
                const char* src = (R < DNROWS)
                    ? (const char*)w_down + (size_t)R * 8192
                    : (const char*)sw_down + (size_t)(R - DNROWS) * 8192;
                wq_f32<8>(src, qdn + (size_t)R * 2048, sd, R, lane);
            }
        }
        return;
    }

    const char* wup  = (const char*)w_up;
    const char* swup = (const char*)sw_up;
    const char* wdn  = (const char*)w_down;
    const char* swdn = (const char*)sw_down;

    u32x4 A0, A1, A2, A3, B0, B1, B2, B3;

#define WQLOAD(P0, P1, P2, P3, T) do { \
        const char* s_ = wq_src((T), wup, swup, wdn, swdn); \
        P0 = ntld16(s_ + lane * 16); \
        P1 = ntld16(s_ + 1024 + lane * 16); \
        P2 = ntld16(s_ + 2048 + lane * 16); \
        P3 = ntld16(s_ + 3072 + lane * 16); \
    } while (0)

#define WQPROC(P0, P1, P2, P3, T) do { \
        if ((T) < UPT2) { \
            const int R0_ = (T) * 2; \
            float m0_ = fmaxf(absmax8(P0), absmax8(P1)); \
            float m1_ = fmaxf(absmax8(P2), absmax8(P3)); \
            m0_ = fmaxf(wredmax(m0_), 1e-12f); \
            m1_ = fmaxf(wredmax(m1_), 1e-12f); \
            if (lane == 0) { su[R0_] = m0_ / 127.f; su[R0_ + 1] = m1_ / 127.f; } \
            char* d_ = qup + (size_t)R0_ * 1024; \
            store8(d_ + lane * 8,        P0, 127.f / m0_); \
            store8(d_ + 512 + lane * 8,  P1, 127.f / m0_); \
            store8(d_ + 1024 + lane * 8, P2, 127.f / m1_); \
            store8(d_ + 1536 + lane * 8, P3, 127.f / m1_); \
        } else { \
            const int R_ = (T) - UPT2; \
            float m_ = fmaxf(fmaxf(absmax8(P0), absmax8(P1)), \
                             fmaxf(absmax8(P2), absmax8(P3))); \
            m_ = fmaxf(wredmax(m_), 1e-12f); \
            if (lane == 0) sd[R_] = m_ / 127.f; \
            const float inv_ = 127.f / m_; \
            char* d_ = qdn + (size_t)R_ * 2048; \
            store8(d_ + lane * 8,        P0, inv_); \
            store8(d_ + 512 + lane * 8,  P1, inv_); \
            store8(d_ + 1024 + lane * 8, P2, inv_); \
            store8(d_ + 1536 + lane * 8, P3, inv_); \
        } \
    } while (0)

    int tA = gwid;
    if (tA >= WQ_NT) return;
    WQLOAD(A0, A1, A2, A3, tA);
    while (true) {
        const int tB = tA + WQ_NW;
        if (tB < WQ_NT) {
            WQLOAD(B0, B1, B2, B3, tB);
            WQPROC(A0, A1, A2, A3, tA);
        } else {
            WQPROC(A0, A1, A2, A3, tA);
            return;
        }
        tA = tB + WQ_NW;
        if (tA < WQ_NT) {
            WQLOAD(A0, A1, A2, A3, tA);
            WQPROC(B0, B1, B2, B3, tB);
        } else {
            WQPROC(B0, B1, B2, B3, tB);
            return;
        }
    }
#undef WQLOAD
#undef WQPROC
}

// -------- Rank: prefix-sum rows per expert --------
__global__ __launch_bounds__(1024) void rank_kernel(
    const int* __restrict__ top_idx, int* __restrict__ tok_rows, int* __restrict__ meta)
{
    __shared__ int wsum[16][NEXP];
    __shared__ int wbase[16][NEXP];
    const int tid = threadIdx.x, lane = tid & 63, wave = tid >> 6;

    const int4* tp = (const int4*)(top_idx + tid * 8);
    int4 v0 = tp[0], v1 = tp[1];
    int e[8] = { v0.x, v0.y, v0.z, v0.w, v1.x, v1.y, v1.z, v1.w };

    int tcnt[NEXP];
    #pragma unroll
    for (int en = 0; en < NEXP; en++) tcnt[en] = 0;
    #pragma unroll
    for (int j = 0; j < 8; j++)
        #pragma unroll
        for (int en = 0; en < NEXP; en++) tcnt[en] += (e[j] == en);

    int excl[NEXP];
    #pragma unroll
    for (int en = 0; en < NEXP; en++) {
        int v = tcnt[en];
        #pragma unroll
        for (int off = 1; off < 64; off <<= 1) {
            int u = __shfl_up(v, off, 64);
            if (lane >= off) v += u;
        }
        excl[en] = v - tcnt[en];
        if (lane == 63) wsum[wave][en] = v;
    }
    __syncthreads();
    if (tid < NEXP) {
        int s = 0;
        for (int w = 0; w < 16; w++) { int c = wsum[w][tid]; wbase[w][tid] = s; s += c; }
        meta[tid] = s;
    }
    __syncthreads();
    if (tid == 0) {
        int b = 0;
        for (int en = 0; en < NEXP; en++) {
            meta[8 + en] = b;
            b += ((meta[en] + 127) >> 7) << 7;
        }
        meta[16] = b;
    }
    __syncthreads();

    int cur[NEXP];
    #pragma unroll
    for (int en = 0; en < NEXP; en++) cur[en] = meta[8 + en] + wbase[wave][en] + excl[en];

    int r[8];
    #pragma unroll
    for (int j = 0; j < 8; j++) {
        int rr = 0;
        #pragma unroll
        for (int en = 0; en < NEXP; en++)
            if (e[j] == en) { rr = cur[en]; cur[en] = rr + 1; }
        r[j] = rr;
    }
    int4* rp = (int4*)(tok_rows + tid * 8);
    rp[0] = make_int4(r[0], r[1], r[2], r[3]);
    rp[1] = make_int4(r[4], r[5], r[6], r[7]);
}

// -------- Gather + per-token int8 quantize: x rows -> xq + sxa --------
__global__ __launch_bounds__(128) void gather_q_kernel(
    const void* __restrict__ x_, const int* __restrict__ tok_rows,
    char* __restrict__ xq, float* __restrict__ sxa, const int* __restrict__ meta)
{
    __shared__ float wmax[2];
    const int t = blockIdx.x, tid = threadIdx.x;
    const int wave = tid >> 6, lane = tid & 63;
    const int r0 = tok_rows[2 * t], r1 = tok_rows[2 * t + 1];

    float v[8];
    if (!meta[30]) {
        u32x4 p = ntld16((const char*)x_ + (size_t)t * DDIM * 2 + tid * 16);
        union { u32x4 v; u16 h[8]; } u; u.v = p;
        #pragma unroll
        for (int d = 0; d < 8; d++) v[d] = bf2f(u.h[d]);
    } else {
        const float4* xf = (const float4*)((const float*)x_ + (size_t)t * DDIM);
        float4 a = xf[2 * tid], b = xf[2 * tid + 1];
        v[0] = a.x; v[1] = a.y; v[2] = a.z; v[3] = a.w;
        v[4] = b.x; v[5] = b.y; v[6] = b.z; v[7] = b.w;
    }
    float m = 0.f;
    #pragma unroll
    for (int d = 0; d < 8; d++) m = fmaxf(m, fabsf(v[d]));
    m = wredmax(m);
    if (lane == 0) wmax[wave] = m;
    __syncthreads();
    const float mx = fmaxf(fmaxf(wmax[0], wmax[1]), 1e-8f);
    const float inv = 127.f / mx;

    u32x2 u;
    u[0] = pack4(v[0], v[1], v[2], v[3], inv);
    u[1] = pack4(v[4], v[5], v[6], v[7], inv);

    ntst8(xq + (size_t)r0 * DDIM + tid * 8, u);
    ntst8(xq + (size_t)r1 * DDIM + tid * 8, u);
    ntst8(xq + (size_t)(SHOFF + t) * DDIM + tid * 8, u);
    if (tid == 0) {
        float s = mx / 127.f;
        sxa[r0] = s; sxa[r1] = s; sxa[SHOFF + t] = s;
    }
}

// ------- Grouped int8 GEMM: 128x128 tile, BK=64, waves 2x2 of 64x64 ----
// mfma_i32_16x16x64_i8, dbuf GLL16, LDS slot swizzle (0 bank conflicts).
// XCD swizzle: L%8 owns a 13-rt band, ct outer / rt inner.
__global__ __launch_bounds__(256, 2) void moe_gemm_i8(
    const char* __restrict__ A, const char* __restrict__ Wq,
    const float* __restrict__ sa, const float* __restrict__ sw,
    u16* __restrict__ Cout, const int* __restrict__ meta, int N, int Kd, int act)
{
    const int L = blockIdx.y * gridDim.x + blockIdx.x;
    const int xcd = L & 7;
    const int jj = L >> 3;
    const int rt = xcd * 13 + (jj % 13);
    const int ct = jj / 13;

    int e;
    if (rt >= RT_TILES) {
        e = NEXP;
    } else {
        const int r0t = rt * 128;
        if (r0t >= meta[16]) return;
        e = 0;
        #pragma unroll
        for (int i = 1; i < NEXP; i++) if (r0t >= meta[8 + i]) e = i;
        if (r0t >= meta[8 + e] + meta[e]) return;
    }
    const char* Wb = Wq + (size_t)(e * N + ct * 128) * Kd;
    const float* swb = sw + e * N + ct * 128;

    __shared__ char As[2][128 * 64];   // 16 KB
    __shared__ char Bs[2][128 * 64];   // 16 KB

    const int tid = threadIdx.x;
    const int wave = tid >> 6, lane = tid & 63;
    const int wm = (wave >> 1) * 64;    // 0 / 64
    const int wn = (wave & 1) * 64;     // 0 / 64
    const int l16 = lane & 15;
    const int q = lane >> 4;
    const int slot = (q + (l16 >> 1)) & 3;

    const int rsub = lane >> 2;                        // 0..15
    const int qs = ((lane & 3) - ((lane >> 3) & 3)) & 3;

    const char* Ag = A + (size_t)(rt * 128 + wave * 16 + rsub) * Kd + qs * 16;
    const char* Bg = Wb + (size_t)(wave * 16 + rsub) * Kd + qs * 16;
    const size_t rstep = (size_t)64 * Kd;

    i32x4 acc[4][4] = {};

#define STAGE(buf, off) do { \
        GLL16(Ag + (off),         &As[buf][wave * 1024]); \
        GLL16(Ag + (off) + rstep, &As[buf][4096 + wave * 1024]); \
        GLL16(Bg + (off),         &Bs[buf][wave * 1024]); \
        GLL16(Bg + (off) + rstep, &Bs[buf][4096 + wave * 1024]); \
    } while (0)

    STAGE(0, 0);
    __syncthreads();

    int cur = 0;
    for (int kk = 0; kk < Kd; kk += 64) {
        if (kk + 64 < Kd) STAGE(cur ^ 1, kk + 64);
        i32x4 af[4], bf[4];
        #pragma unroll
        for (int i = 0; i < 4; i++)
            af[i] = *(const i32x4*)&As[cur][(wm + i * 16 + l16) * 64 + slot * 16];
        #pragma unroll
        for (int j = 0; j < 4; j++)
            bf[j] = *(const i32x4*)&Bs[cur][(wn + j * 16 + l16) * 64 + slot * 16];
        #pragma unroll
        for (int i = 0; i < 4; i++)
            #pragma unroll
            for (int j = 0; j < 4; j++)
                acc[i][j] = __builtin_amdgcn_mfma_i32_16x16x64_i8(af[i], bf[j], acc[i][j], 0, 0, 0);
        __syncthreads();
        cur ^= 1;
    }
#undef STAGE

    float sal[4][4];
    #pragma unroll
    for (int i = 0; i < 4; i++)
        #pragma unroll
        for (int rr = 0; rr < 4; rr++)
            sal[i][rr] = sa[rt * 128 + wm + i * 16 + q * 4 + rr];
    float swl[4];
    #pragma unroll
    for (int j = 0; j < 4; j++) swl[j] = swb[wn + j * 16 + l16];

    u16* Crow = Cout + (size_t)(rt * 128) * N + ct * 128;
    #pragma unroll
    for (int i = 0; i < 4; i++) {
        #pragma unroll
        for (int j = 0; j < 4; j++) {
            #pragma unroll
            for (int rr = 0; rr < 4; rr++) {
                const int row = wm + i * 16 + q * 4 + rr;
                const int col = wn + j * 16 + l16;
                float v = (float)acc[i][j][rr] * sal[i][rr] * swl[j];
                if (act) v = v / (1.f + __expf(-v));   // SiLU
                Crow[(size_t)row * N + col] = f2bf(v);
            }
        }
    }
}

// ---- h quantize: PERSISTENT, nt streaming, wave-per-row (4 KB tasks) ----
__global__ __launch_bounds__(256) void hquant_kernel(
    const u16* __restrict__ hg, char* __restrict__ h8, float* __restrict__ sh,
    const int* __restrict__ meta)
{
    const int gwid = (blockIdx.x * blockDim.x + threadIdx.x) >> 6;  // 0..WQ_NW-1
    const int lane = threadIdx.x & 63;
    const int m16 = meta[16];
    const int NT = m16 + (RCAP - SHOFF);   // valid rows (routed + shared)
    const int gap = SHOFF - m16;
    if (gwid >= NT) return;

    u32x4 A0, A1, A2, A3, B0, B1, B2, B3;

#define HROW(T) ((T) < m16 ? (T) : (T) + gap)
#define HLOAD(P0, P1, P2, P3, T) do { \
        const char* r_ = (const char*)(hg + (size_t)HROW(T) * FDIM); \
        P0 = ntld16(r_ + lane * 16); \
        P1 = ntld16(r_ + 1024 + lane * 16); \
        P2 = ntld16(r_ + 2048 + lane * 16); \
        P3 = ntld16(r_ + 3072 + lane * 16); \
    } while (0)
#define HPROC(P0, P1, P2, P3, T) do { \
        const int r_ = HROW(T); \
        float m_ = fmaxf(fmaxf(absmax8(P0), absmax8(P1)), \
                         fmaxf(absmax8(P2), absmax8(P3))); \
        m_ = fmaxf(wredmax(m_), 1e-8f); \
        if (lane == 0) sh[r_] = m_ / 127.f; \
        const float inv_ = 127.f / m_; \
        char* d_ = h8 + (size_t)r_ * FDIM; \
        store8(d_ + lane * 8,        P0, inv_); \
        store8(d_ + 512 + lane * 8,  P1, inv_); \
        store8(d_ + 1024 + lane * 8, P2, inv_); \
        store8(d_ + 1536 + lane * 8, P3, inv_); \
    } while (0)

    int tA = gwid;
    HLOAD(A0, A1, A2, A3, tA);
    while (true) {
        const int tB = tA + WQ_NW;
        if (tB < NT) {
            HLOAD(B0, B1, B2, B3, tB);
            HPROC(A0, A1, A2, A3, tA);
        } else {
            HPROC(A0, A1, A2, A3, tA);
            return;
        }
        tA = tB + WQ_NW;
        if (tA < NT) {
            HLOAD(A0, A1, A2, A3, tA);
            HPROC(B0, B1, B2, B3, tB);
        } else {
            HPROC(B0, B1, B2, B3, tB);
            return;
        }
    }
#undef HROW
#undef HLOAD
#undef HPROC
}

// ---------------- Combine ----------------
__global__ __launch_bounds__(256) void combine_kernel(
    const u16* __restrict__ yg, const float* __restrict__ top_w,
    const int* __restrict__ tok_rows, void* __restrict__ out_, const int* __restrict__ meta)
{
    const int t = blockIdx.x;
    const int r0 = tok_rows[2 * t], r1 = tok_rows[2 * t + 1];
    const float w0 = top_w[2 * t], w1 = top_w[2 * t + 1];
    const int d = threadIdx.x * 4;
    union { u32x2 v; u16 h[4]; } y0, y1, ys;
    y0.v = ntld8((const char*)(yg + (size_t)r0 * DDIM + d));
    y1.v = ntld8((const char*)(yg + (size_t)r1 * DDIM + d));
    ys.v = ntld8((const char*)(yg + (size_t)(SHOFF + t) * DDIM + d));
    float o0 = w0 * bf2f(y0.h[0]) + w1 * bf2f(y1.h[0]) + bf2f(ys.h[0]);
    float o1 = w0 * bf2f(y0.h[1]) + w1 * bf2f(y1.h[1]) + bf2f(ys.h[1]);
    float o2 = w0 * bf2f(y0.h[2]) + w1 * bf2f(y1.h[2]) + bf2f(ys.h[2]);
    float o3 = w0 * bf2f(y0.h[3]) + w1 * bf2f(y1.h[3]) + bf2f(ys.h[3]);
    if (!meta[30]) {
        union { u32x2 v; u16 h[4]; } o;
        o.h[0] = f2bf(o0); o.h[1] = f2bf(o1); o.h[2] = f2bf(o2); o.h[3] = f2bf(o3);
        ntst8((char*)((u16*)out_ + (size_t)t * DDIM + d), o.v);
    } else {
        float4 o; o.x = o0; o.y = o1; o.z = o2; o.w = o3;
        *(float4*)((float*)out_ + (size_t)t * DDIM + d) = o;
    }
}

extern "C" void kernel_launch(void* const* d_in, const int* in_sizes, int n_in,
                              void* d_out, int out_size, void* d_ws, size_t ws_size,
                              hipStream_t stream) {
    const void* x       = d_in[0];
    const void* rw      = d_in[1];
    const void* rb      = d_in[2];
    const void* w_up    = d_in[3];
    const void* w_down  = d_in[4];
    const void* sw_up   = d_in[5];
    const void* sw_down = d_in[6];

    const int T = in_sizes[0] / DDIM;  // 4096

    char* ws = (char*)d_ws;
    int*   meta     = (int*)ws;
    float* top_w    = (float*)(ws + 1024);
    int*   top_idx  = (int*)(ws + 1024 + 8 * T);
    int*   tok_rows = (int*)(ws + 1024 + 16 * T);
    size_t off = 131072;
    u16*  yg = (u16*)(ws + off);            // down output (bf16)
    char* xq = (char*)(ws + off);           // aliased: xq dead before yg written
    off += (size_t)RCAP * DDIM * 2;
    u16*  hg = (u16*)(ws + off);            // up output (bf16)
    off += (size_t)RCAP * FDIM * 2;
    char* h8 = (char*)(ws + off);
    off += (size_t)RCAP * FDIM;
    char* qup = (char*)(ws + off);
    off += (size_t)(NEXP + 1) * FDIM * DDIM;
    char* qdn = (char*)(ws + off);
    off += (size_t)(NEXP + 1) * DDIM * FDIM;
    float* sxa = (float*)(ws + off); off += (size_t)RCAP * 4;
    float* sh  = (float*)(ws + off); off += (size_t)RCAP * 4;
    float* su  = (float*)(ws + off); off += (size_t)(NEXP + 1) * FDIM * 4;
    float* sd  = (float*)(ws + off); off += (size_t)(NEXP + 1) * DDIM * 4;

    detect_kernel<<<1, 256, 0, stream>>>((const u16*)x, meta);

    const int nrb = T / 16;  // 256 router blocks
    router_kernel<<<nrb, 256, 0, stream>>>(x, rw, rb, top_w, top_idx, meta);
    wquant_kernel<<<WQ_NW / 4, 256, 0, stream>>>(
        w_up, w_down, sw_up, sw_down, qup, qdn, su, sd, meta);
    rank_kernel<<<1, 1024, 0, stream>>>(top_idx, tok_rows, meta);
    gather_q_kernel<<<T, 128, 0, stream>>>(x, tok_rows, xq, sxa, meta);

    // Up: [RCAP,1024]i8 x [9*2048,1024]i8 -> hg bf16 (SiLU fused)
    moe_gemm_i8<<<dim3(FDIM / 128, NRT), 256, 0, stream>>>(
        xq, qup, sxa, su, hg, meta, FDIM, DDIM, 1);
    hquant_kernel<<<WQ_NW / 4, 256, 0, stream>>>(hg, h8, sh, meta);
    moe_gemm_i8<<<dim3(DDIM / 128, NRT), 256, 0, stream>>>(
        h8, qdn, sh, sd, yg, meta, DDIM, FDIM, 0);
    combine_kernel<<<T, 256, 0, stream>>>(yg, top_w, tok_rows, d_out, meta);
}

// Round 8
// 311.038 us; speedup vs baseline: 1.0490x; 1.0490x over previous
//
#include <hip/hip_runtime.h>
#include <stdint.h>

typedef unsigned short u16;
typedef int i32x4 __attribute__((ext_vector_type(4)));
typedef unsigned int u32x4 __attribute__((ext_vector_type(4)));
typedef unsigned int u32x2 __attribute__((ext_vector_type(2)));

#define DDIM 1024
#define FDIM 2048
#define NEXP 8
#define RT_TILES 72      /* routed row tiles: 9216/128 */
#define SHOFF 9216       /* start row of shared-expert segment */
#define RCAP 13312       /* 9216 routed (padded) + 4096 shared rows */
#define NRT 104          /* RCAP/128 row tiles */
#define UPROWS 16384     /* NEXP*FDIM routed up rows */
#define DNROWS 8192      /* NEXP*DDIM routed down rows */
#define UPTOT (UPROWS + FDIM)    /* 18432 up rows incl. shared */
#define DNTOT (DNROWS + DDIM)    /* 9216 down rows incl. shared */
#define UPT2 (UPTOT / 2)         /* 9216 two-row up tasks (4 KB each) */
#define WQW 4608                 /* wq waves per role: 1152 blocks x 4 */
#define NG_UP 1664               /* up-GEMM blocks: 8 xcd * 13 rt * 16 ct */

// meta: [0..7] counts, [8..15] base[e], [16] total_padded, [30] dtype flag (1=fp32 inputs)

__device__ inline float bf2f(u16 u) {
    union { unsigned int i; float f; } v; v.i = ((unsigned int)u) << 16; return v.f;
}
__device__ inline u16 f2bf(float f) {
    union { float f; unsigned int i; } v; v.f = f;
    unsigned int lsb = (v.i >> 16) & 1u;
    return (u16)((v.i + 0x7fffu + lsb) >> 16);
}
__device__ inline int q8(float v, float inv) {
    int x = (int)rintf(v * inv);
    return x < -127 ? -127 : (x > 127 ? 127 : x);
}
__device__ inline unsigned pack4(float a, float b, float c, float d, float inv) {
    return (unsigned)(q8(a, inv) & 255) | ((unsigned)(q8(b, inv) & 255) << 8) |
           ((unsigned)(q8(c, inv) & 255) << 16) | ((unsigned)(q8(d, inv) & 255) << 24);
}

// ---- non-temporal (L1-bypass / streaming) access helpers ----
__device__ inline u32x4 ntld16(const char* p) {
    return __builtin_nontemporal_load((const u32x4*)p);
}
__device__ inline u32x2 ntld8(const char* p) {
    return __builtin_nontemporal_load((const u32x2*)p);
}
__device__ inline void ntst8(char* p, u32x2 v) {
    __builtin_nontemporal_store(v, (u32x2*)p);
}

__device__ inline float absmax8(u32x4 p) {
    union { u32x4 v; u16 h[8]; } u; u.v = p;
    float m = fabsf(bf2f(u.h[0]));
    #pragma unroll
    for (int d = 1; d < 8; d++) m = fmaxf(m, fabsf(bf2f(u.h[d])));
    return m;
}
__device__ inline void store8(char* dst, u32x4 p, float inv) {
    union { u32x4 v; u16 h[8]; } u; u.v = p;
    u32x2 o;
    o[0] = pack4(bf2f(u.h[0]), bf2f(u.h[1]), bf2f(u.h[2]), bf2f(u.h[3]), inv);
    o[1] = pack4(bf2f(u.h[4]), bf2f(u.h[5]), bf2f(u.h[6]), bf2f(u.h[7]), inv);
    ntst8(dst, o);
}
__device__ inline float wredmax(float m) {
    #pragma unroll
    for (int off = 32; off > 0; off >>= 1) m = fmaxf(m, __shfl_xor(m, off, 64));
    return m;
}

typedef const __attribute__((address_space(1))) void gas_void;
typedef __attribute__((address_space(3))) void las_void;
#define GLL16(g, l) __builtin_amdgcn_global_load_lds((gas_void*)(g), (las_void*)(l), 16, 0, 0)

// Per-block dtype detect over first 1024 halfwords of x.
__device__ inline int detect_inline(const u16* __restrict__ x, int* sh) {
    if (threadIdx.x == 0) *sh = 0;
    __syncthreads();
    const int per = 1024 / blockDim.x;
    int bad = 0;
    for (int i = 0; i < per; i++) {
        u16 v = x[threadIdx.x * per + i];
        if (((v >> 7) & 0xFF) >= 0x8F) bad++;
    }
    if (bad) atomicAdd(sh, bad);
    __syncthreads();
    return (*sh > 32) ? 1 : 0;
}

// fp32 fallback weight quant: two-pass global read (2nd pass L2-hits).
template<int NC>
__device__ inline void wq_f32(const char* __restrict__ src, char* __restrict__ dst,
                              float* __restrict__ sout, int R, int lane) {
    float m = 0.f;
    #pragma unroll
    for (int c = 0; c < NC; c++) {
        float4 f = *(const float4*)(src + (size_t)c * 1024 + lane * 16);
        m = fmaxf(m, fmaxf(fmaxf(fabsf(f.x), fabsf(f.y)),
                           fmaxf(fabsf(f.z), fabsf(f.w))));
    }
    m = wredmax(m);
    m = fmaxf(m, 1e-12f);
    if (lane == 0) sout[R] = m / 127.f;
    const float inv = 127.f / m;
    #pragma unroll
    for (int c = 0; c < NC; c++) {
        float4 f = *(const float4*)(src + (size_t)c * 1024 + lane * 16);
        *(unsigned*)(dst + (size_t)c * 256 + lane * 4) = pack4(f.x, f.y, f.z, f.w, inv);
    }
}

// ======== K1: router blocks [0,nrb) + weight-quant-UP blocks [nrb,nrb+1152) ====
// Router: 16 tokens/block, fp32 logits -> top2. wq-up: 2 tasks/wave, 2 rows/task.
// Co-scheduling rationale: router is LDS/VALU-heavy, wq-up is pure HBM streaming.
__global__ __launch_bounds__(256) void fused_rw_kernel(
    const void* __restrict__ x_, const void* __restrict__ rw_, const void* __restrict__ rb_,
    const void* __restrict__ w_up, const void* __restrict__ sw_up,
    float* __restrict__ top_w, int* __restrict__ top_idx,
    char* __restrict__ qup, float* __restrict__ su, int nrb)
{
    __shared__ char smem[32768 + 16];
    const int tid = threadIdx.x;
    const int wave = tid >> 6, lane = tid & 63;
    const int flag = detect_inline((const u16*)x_, (int*)(smem + 32768));

    if ((int)blockIdx.x < nrb) {
        // ---------------- router path ----------------
        float* rws = (float*)smem;
        if (!flag) {
            const ushort4* rwv = (const ushort4*)rw_;
            #pragma unroll
            for (int i = 0; i < 8; i++) {
                int idx = tid + i * 256;
                ushort4 h = rwv[idx];
                rws[idx * 4 + 0] = bf2f(h.x); rws[idx * 4 + 1] = bf2f(h.y);
                rws[idx * 4 + 2] = bf2f(h.z); rws[idx * 4 + 3] = bf2f(h.w);
            }
        } else {
            const float4* rwv = (const float4*)rw_;
            #pragma unroll
            for (int i = 0; i < 8; i++) {
                int idx = tid + i * 256;
                float4 f = rwv[idx];
                rws[idx * 4 + 0] = f.x; rws[idx * 4 + 1] = f.y;
                rws[idx * 4 + 2] = f.z; rws[idx * 4 + 3] = f.w;
            }
        }
        __syncthreads();

        for (int sub = 0; sub < 4; sub++) {
            const int t = blockIdx.x * 16 + wave * 4 + sub;
            float xv[16];
            if (!flag) {
                const u16* xr = (const u16*)x_ + (size_t)t * DDIM + lane * 16;
                uint4 p0 = *(const uint4*)(xr);
                uint4 p1 = *(const uint4*)(xr + 8);
                #pragma unroll
                for (int d = 0; d < 8; d++) xv[d]     = bf2f(((const u16*)&p0)[d]);
                #pragma unroll
                for (int d = 0; d < 8; d++) xv[d + 8] = bf2f(((const u16*)&p1)[d]);
            } else {
                const float4* xr = (const float4*)((const float*)x_ + (size_t)t * DDIM + lane * 16);
                #pragma unroll
                for (int c = 0; c < 4; c++) {
                    float4 f = xr[c];
                    xv[c * 4 + 0] = f.x; xv[c * 4 + 1] = f.y;
                    xv[c * 4 + 2] = f.z; xv[c * 4 + 3] = f.w;
                }
            }
            float acc[NEXP];
            #pragma unroll
            for (int e = 0; e < NEXP; e++) {
                const float* wr = &rws[e * DDIM + lane * 16];
                float s = 0.f;
                #pragma unroll
                for (int d = 0; d < 16; d++) s += xv[d] * wr[d];
                acc[e] = s;
            }
            #pragma unroll
            for (int e = 0; e < NEXP; e++) {
                #pragma unroll
                for (int off = 32; off > 0; off >>= 1)
                    acc[e] += __shfl_xor(acc[e], off, 64);
            }
            if (lane == 0) {
                float lg[NEXP];
                #pragma unroll
                for (int e = 0; e < NEXP; e++) {
                    float b = flag ? ((const float*)rb_)[e] : bf2f(((const u16*)rb_)[e]);
                    lg[e] = acc[e] + b;
                }
                int i0 = 0;
                #pragma unroll
                for (int e = 1; e < NEXP; e++) if (lg[e] > lg[i0]) i0 = e;
                int i1 = (i0 == 0) ? 1 : 0;
                #pragma unroll
                for (int e = 0; e < NEXP; e++) if (e != i0 && lg[e] > lg[i1]) i1 = e;
                float e1 = __expf(lg[i1] - lg[i0]);
                float w0 = 1.f / (1.f + e1);
                float w1 = e1 / (1.f + e1);
                top_w[2 * t] = w0;  top_w[2 * t + 1] = w1;
                top_idx[2 * t] = i0; top_idx[2 * t + 1] = i1;
            }
        }
        return;
    }

    // ---------------- wq-up path: 2 tasks/wave, 2 rows (4 KB) per task --------
    const int gwid = ((int)blockIdx.x - nrb) * 4 + wave;   // 0..4607
    if (!flag) {
        for (int t = gwid; t < UPT2; t += WQW) {
            const int R0 = t * 2;
            const char* src = (R0 < UPROWS)
                ? (const char*)w_up + (size_t)R0 * 2048
                : (const char*)sw_up + (size_t)(R0 - UPROWS) * 2048;
            u32x4 P0 = ntld16(src + lane * 16);
            u32x4 P1 = ntld16(src + 1024 + lane * 16);
            u32x4 P2 = ntld16(src + 2048 + lane * 16);
            u32x4 P3 = ntld16(src + 3072 + lane * 16);
            float m0 = fmaxf(absmax8(P0), absmax8(P1));
            float m1 = fmaxf(absmax8(P2), absmax8(P3));
            m0 = fmaxf(wredmax(m0), 1e-12f);
            m1 = fmaxf(wredmax(m1), 1e-12f);
            if (lane == 0) { su[R0] = m0 / 127.f; su[R0 + 1] = m1 / 127.f; }
            char* d = qup + (size_t)R0 * 1024;
            store8(d + lane * 8,        P0, 127.f / m0);
            store8(d + 512 + lane * 8,  P1, 127.f / m0);
            store8(d + 1024 + lane * 8, P2, 127.f / m1);
            store8(d + 1536 + lane * 8, P3, 127.f / m1);
        }
    } else {
        for (int t = gwid; t < UPT2; t += WQW) {
            const int R0 = t * 2;
            const char* src = (R0 < UPROWS)
                ? (const char*)w_up + (size_t)R0 * 4096
                : (const char*)sw_up + (size_t)(R0 - UPROWS) * 4096;
            wq_f32<4>(src,        qup + (size_t)R0 * 1024,       su, R0,     lane);
            wq_f32<4>(src + 4096, qup + (size_t)(R0 + 1) * 1024, su, R0 + 1, lane);
        }
    }
}

// -------- Rank: prefix-sum rows per expert; publishes dtype flag --------
__global__ __launch_bounds__(1024) void rank_kernel(
    const u16* __restrict__ x, const int* __restrict__ top_idx,
    int* __restrict__ tok_rows, int* __restrict__ meta)
{
    __shared__ int wsum[16][NEXP];
    __shared__ int wbase[16][NEXP];
    __shared__ int scnt;
    const int tid = threadIdx.x, lane = tid & 63, wave = tid >> 6;

    const int flag = detect_inline(x, &scnt);
    if (tid == 0) meta[30] = flag;

    const int4* tp = (const int4*)(top_idx + tid * 8);
    int4 v0 = tp[0], v1 = tp[1];
    int e[8] = { v0.x, v0.y, v0.z, v0.w, v1.x, v1.y, v1.z, v1.w };

    int tcnt[NEXP];
    #pragma unroll
    for (int en = 0; en < NEXP; en++) tcnt[en] = 0;
    #pragma unroll
    for (int j = 0; j < 8; j++)
        #pragma unroll
        for (int en = 0; en < NEXP; en++) tcnt[en] += (e[j] == en);

    int excl[NEXP];
    #pragma unroll
    for (int en = 0; en < NEXP; en++) {
        int v = tcnt[en];
        #pragma unroll
        for (int off = 1; off < 64; off <<= 1) {
            int u = __shfl_up(v, off, 64);
            if (lane >= off) v += u;
        }
        excl[en] = v - tcnt[en];
        if (lane == 63) wsum[wave][en] = v;
    }
    __syncthreads();
    if (tid < NEXP) {
        int s = 0;
        for (int w = 0; w < 16; w++) { int c = wsum[w][tid]; wbase[w][tid] = s; s += c; }
        meta[tid] = s;
    }
    __syncthreads();
    if (tid == 0) {
        int b = 0;
        for (int en = 0; en < NEXP; en++) {
            meta[8 + en] = b;
            b += ((meta[en] + 127) >> 7) << 7;
        }
        meta[16] = b;
    }
    __syncthreads();

    int cur[NEXP];
    #pragma unroll
    for (int en = 0; en < NEXP; en++) cur[en] = meta[8 + en] + wbase[wave][en] + excl[en];

    int r[8];
    #pragma unroll
    for (int j = 0; j < 8; j++) {
        int rr = 0;
        #pragma unroll
        for (int en = 0; en < NEXP; en++)
            if (e[j] == en) { rr = cur[en]; cur[en] = rr + 1; }
        r[j] = rr;
    }
    int4* rp = (int4*)(tok_rows + tid * 8);
    rp[0] = make_int4(r[0], r[1], r[2], r[3]);
    rp[1] = make_int4(r[4], r[5], r[6], r[7]);
}

// -------- Gather + per-token int8 quantize: x rows -> xq + sxa --------
__global__ __launch_bounds__(128) void gather_q_kernel(
    const void* __restrict__ x_, const int* __restrict__ tok_rows,
    char* __restrict__ xq, float* __restrict__ sxa, const int* __restrict__ meta)
{
    __shared__ float wmax[2];
    const int t = blockIdx.x, tid = threadIdx.x;
    const int wave = tid >> 6, lane = tid & 63;
    const int r0 = tok_rows[2 * t], r1 = tok_rows[2 * t + 1];

    float v[8];
    if (!meta[30]) {
        u32x4 p = ntld16((const char*)x_ + (size_t)t * DDIM * 2 + tid * 16);
        union { u32x4 v; u16 h[8]; } u; u.v = p;
        #pragma unroll
        for (int d = 0; d < 8; d++) v[d] = bf2f(u.h[d]);
    } else {
        const float4* xf = (const float4*)((const float*)x_ + (size_t)t * DDIM);
        float4 a = xf[2 * tid], b = xf[2 * tid + 1];
        v[0] = a.x; v[1] = a.y; v[2] = a.z; v[3] = a.w;
        v[4] = b.x; v[5] = b.y; v[6] = b.z; v[7] = b.w;
    }
    float m = 0.f;
    #pragma unroll
    for (int d = 0; d < 8; d++) m = fmaxf(m, fabsf(v[d]));
    m = wredmax(m);
    if (lane == 0) wmax[wave] = m;
    __syncthreads();
    const float mx = fmaxf(fmaxf(wmax[0], wmax[1]), 1e-8f);
    const float inv = 127.f / mx;

    u32x2 u;
    u[0] = pack4(v[0], v[1], v[2], v[3], inv);
    u[1] = pack4(v[4], v[5], v[6], v[7], inv);

    ntst8(xq + (size_t)r0 * DDIM + tid * 8, u);
    ntst8(xq + (size_t)r1 * DDIM + tid * 8, u);
    ntst8(xq + (size_t)(SHOFF + t) * DDIM + tid * 8, u);
    if (tid == 0) {
        float s = mx / 127.f;
        sxa[r0] = s; sxa[r1] = s; sxa[SHOFF + t] = s;
    }
}

// ==== K4: up-GEMM blocks [0,1664) + weight-quant-DOWN blocks [1664,2816) ====
// GEMM: 128x128 tile, BK=64, mfma_i32_16x16x64_i8, dbuf GLL16, slot swizzle,
// XCD band swizzle. wq-dn streams w_down -> qdn concurrently (disjoint pipes:
// GEMM is MFMA/LDS-bound at ~10% HBM; wq-dn is pure HBM streaming).
__global__ __launch_bounds__(256, 2) void gemm_up_wqdn(
    const char* __restrict__ A, const char* __restrict__ Wq,
    const float* __restrict__ sa, const float* __restrict__ sw,
    u16* __restrict__ Cout, const int* __restrict__ meta,
    const void* __restrict__ w_down, const void* __restrict__ sw_down,
    char* __restrict__ qdn, float* __restrict__ sd)
{
    __shared__ char As[2][128 * 64];   // 16 KB
    __shared__ char Bs[2][128 * 64];   // 16 KB

    const int bid = blockIdx.x;
    const int tid = threadIdx.x;
    const int wave = tid >> 6, lane = tid & 63;

    if (bid >= NG_UP) {
        // ---------------- wq-down role: 2 tasks/wave, 1 row (4 KB) per task ----
        const int gwid = (bid - NG_UP) * 4 + wave;   // 0..4607
        const int flag = meta[30];
        if (!flag) {
            for (int R = gwid; R < DNTOT; R += WQW) {
                const char* src = (R < DNROWS)
                    ? (const char*)w_down + (size_t)R * 4096
                    : (const char*)sw_down + (size_t)(R - DNROWS) * 4096;
                u32x4 P0 = ntld16(src + lane * 16);
                u32x4 P1 = ntld16(src + 1024 + lane * 16);
                u32x4 P2 = ntld16(src + 2048 + lane * 16);
                u32x4 P3 = ntld16(src + 3072 + lane * 16);
                float m = fmaxf(fmaxf(absmax8(P0), absmax8(P1)),
                                fmaxf(absmax8(P2), absmax8(P3)));
                m = fmaxf(wredmax(m), 1e-12f);
                if (lane == 0) sd[R] = m / 127.f;
                const float inv = 127.f / m;
                char* d = qdn + (size_t)R * 2048;
                store8(d + lane * 8,        P0, inv);
                store8(d + 512 + lane * 8,  P1, inv);
                store8(d + 1024 + lane * 8, P2, inv);
                store8(d + 1536 + lane * 8, P3, inv);
            }
        } else {
            for (int R = gwid; R < DNTOT; R += WQW) {
                const char* src = (R < DNROWS)
                    ? (const char*)w_down + (size_t)R * 8192
                    : (const char*)sw_down + (size_t)(R - DNROWS) * 8192;
                wq_f32<8>(src, qdn + (size_t)R * 2048, sd, R, lane);
            }
        }
        return;
    }

    // ---------------- up-GEMM role (N=FDIM, Kd=DDIM, act=SiLU) ----------------
    const int xcd = bid & 7;
    const int jj = bid >> 3;
    const int rt = xcd * 13 + (jj % 13);
    const int ct = jj / 13;

    int e;
    if (rt >= RT_TILES) {
        e = NEXP;
    } else {
        const int r0t = rt * 128;
        if (r0t >= meta[16]) return;
        e = 0;
        #pragma unroll
        for (int i = 1; i < NEXP; i++) if (r0t >= meta[8 + i]) e = i;
        if (r0t >= meta[8 + e] + meta[e]) return;
    }
    const char* Wb = Wq + (size_t)(e * FDIM + ct * 128) * DDIM;
    const float* swb = sw + e * FDIM + ct * 128;

    const int wm = (wave >> 1) * 64;    // 0 / 64
    const int wn = (wave & 1) * 64;     // 0 / 64
    const int l16 = lane & 15;
    const int q = lane >> 4;
    const int slot = (q + (l16 >> 1)) & 3;

    const int rsub = lane >> 2;                        // 0..15
    const int qs = ((lane & 3) - ((lane >> 3) & 3)) & 3;

    const char* Ag = A + (size_t)(rt * 128 + wave * 16 + rsub) * DDIM + qs * 16;
    const char* Bg = Wb + (size_t)(wave * 16 + rsub) * DDIM + qs * 16;
    const size_t rstep = (size_t)64 * DDIM;

    i32x4 acc[4][4] = {};

#define STAGE(buf, off) do { \
        GLL16(Ag + (off),         &As[buf][wave * 1024]); \
        GLL16(Ag + (off) + rstep, &As[buf][4096 + wave * 1024]); \
        GLL16(Bg + (off),         &Bs[buf][wave * 1024]); \
        GLL16(Bg + (off) + rstep, &Bs[buf][4096 + wave * 1024]); \
    } while (0)

    STAGE(0, 0);
    __syncthreads();

    int cur = 0;
    for (int kk = 0; kk < DDIM; kk += 64) {
        if (kk + 64 < DDIM) STAGE(cur ^ 1, kk + 64);
        i32x4 af[4], bf[4];
        #pragma unroll
        for (int i = 0; i < 4; i++)
            af[i] = *(const i32x4*)&As[cur][(wm + i * 16 + l16) * 64 + slot * 16];
        #pragma unroll
        for (int j = 0; j < 4; j++)
            bf[j] = *(const i32x4*)&Bs[cur][(wn + j * 16 + l16) * 64 + slot * 16];
        #pragma unroll
        for (int i = 0; i < 4; i++)
            #pragma unroll
            for (int j = 0; j < 4; j++)
                acc[i][j] = __builtin_amdgcn_mfma_i32_16x16x64_i8(af[i], bf[j], acc[i][j], 0, 0, 0);
        __syncthreads();
        cur ^= 1;
    }
#undef STAGE

    float sal[4][4];
    #pragma unroll
    for (int i = 0; i < 4; i++)
        #pragma unroll
        for (int rr = 0; rr < 4; rr++)
            sal[i][rr] = sa[rt * 128 + wm + i * 16 + q * 4 + rr];
    float swl[4];
    #pragma unroll
    for (int j = 0; j < 4; j++) swl[j] = swb[wn + j * 16 + l16];

    u16* Crow = Cout + (size_t)(rt * 128) * FDIM + ct * 128;
    #pragma unroll
    for (int i = 0; i < 4; i++) {
        #pragma unroll
        for (int j = 0; j < 4; j++) {
            #pragma unroll
            for (int rr = 0; rr < 4; rr++) {
                const int row = wm + i * 16 + q * 4 + rr;
                const int col = wn + j * 16 + l16;
                float v = (float)acc[i][j][rr] * sal[i][rr] * swl[j];
                v = v / (1.f + __expf(-v));   // SiLU
                Crow[(size_t)row * FDIM + col] = f2bf(v);
            }
        }
    }
}

// ------- Down GEMM: 128x128 tile, BK=64 (generic, runtime N/Kd/act) ----
__global__ __launch_bounds__(256, 2) void moe_gemm_i8(
    const char* __restrict__ A, const char* __restrict__ Wq,
    const float* __restrict__ sa, const float* __restrict__ sw,
    u16* __restrict__ Cout, const int* __restrict__ meta, int N, int Kd, int act)
{
    const int L = blockIdx.y * gridDim.x + blockIdx.x;
    const int xcd = L & 7;
    const int jj = L >> 3;
    const int rt = xcd * 13 + (jj % 13);
    const int ct = jj / 13;

    int e;
    if (rt >= RT_TILES) {
        e = NEXP;
    } else {
        const int r0t = rt * 128;
        if (r0t >= meta[16]) return;
        e = 0;
        #pragma unroll
        for (int i = 1; i < NEXP; i++) if (r0t >= meta[8 + i]) e = i;
        if (r0t >= meta[8 + e] + meta[e]) return;
    }
    const char* Wb = Wq + (size_t)(e * N + ct * 128) * Kd;
    const float* swb = sw + e * N + ct * 128;

    __shared__ char As[2][128 * 64];   // 16 KB
    __shared__ char Bs[2][128 * 64];   // 16 KB

    const int tid = threadIdx.x;
    const int wave = tid >> 6, lane = tid & 63;
    const int wm = (wave >> 1) * 64;    // 0 / 64
    const int wn = (wave & 1) * 64;     // 0 / 64
    const int l16 = lane & 15;
    const int q = lane >> 4;
    const int slot = (q + (l16 >> 1)) & 3;

    const int rsub = lane >> 2;                        // 0..15
    const int qs = ((lane & 3) - ((lane >> 3) & 3)) & 3;

    const char* Ag = A + (size_t)(rt * 128 + wave * 16 + rsub) * Kd + qs * 16;
    const char* Bg = Wb + (size_t)(wave * 16 + rsub) * Kd + qs * 16;
    const size_t rstep = (size_t)64 * Kd;

    i32x4 acc[4][4] = {};

#define STAGE(buf, off) do { \
        GLL16(Ag + (off),         &As[buf][wave * 1024]); \
        GLL16(Ag + (off) + rstep, &As[buf][4096 + wave * 1024]); \
        GLL16(Bg + (off),         &Bs[buf][wave * 1024]); \
        GLL16(Bg + (off) + rstep, &Bs[buf][4096 + wave * 1024]); \
    } while (0)

    STAGE(0, 0);
    __syncthreads();

    int cur = 0;
    for (int kk = 0; kk < Kd; kk += 64) {
        if (kk + 64 < Kd) STAGE(cur ^ 1, kk + 64);
        i32x4 af[4], bf[4];
        #pragma unroll
        for (int i = 0; i < 4; i++)
            af[i] = *(const i32x4*)&As[cur][(wm + i * 16 + l16) * 64 + slot * 16];
        #pragma unroll
        for (int j = 0; j < 4; j++)
            bf[j] = *(const i32x4*)&Bs[cur][(wn + j * 16 + l16) * 64 + slot * 16];
        #pragma unroll
        for (int i = 0; i < 4; i++)
            #pragma unroll
            for (int j = 0; j < 4; j++)
                acc[i][j] = __builtin_amdgcn_mfma_i32_16x16x64_i8(af[i], bf[j], acc[i][j], 0, 0, 0);
        __syncthreads();
        cur ^= 1;
    }
#undef STAGE

    float sal[4][4];
    #pragma unroll
    for (int i = 0; i < 4; i++)
        #pragma unroll
        for (int rr = 0; rr < 4; rr++)
            sal[i][rr] = sa[rt * 128 + wm + i * 16 + q * 4 + rr];
    float swl[4];
    #pragma unroll
    for (int j = 0; j < 4; j++) swl[j] = swb[wn + j * 16 + l16];

    u16* Crow = Cout + (size_t)(rt * 128) * N + ct * 128;
    #pragma unroll
    for (int i = 0; i < 4; i++) {
        #pragma unroll
        for (int j = 0; j < 4; j++) {
            #pragma unroll
            for (int rr = 0; rr < 4; rr++) {
                const int row = wm + i * 16 + q * 4 + rr;
                const int col = wn + j * 16 + l16;
                float v = (float)acc[i][j][rr] * sal[i][rr] * swl[j];
                if (act) v = v / (1.f + __expf(-v));   // SiLU
                Crow[(size_t)row * N + col] = f2bf(v);
            }
        }
    }
}

// ---- h quantize: PERSISTENT, nt streaming, wave-per-row (4 KB tasks) ----
__global__ __launch_bounds__(256) void hquant_kernel(
    const u16* __restrict__ hg, char* __restrict__ h8, float* __restrict__ sh,
    const int* __restrict__ meta)
{
    const int gwid = (blockIdx.x * blockDim.x + threadIdx.x) >> 6;  // 0..4095
    const int lane = threadIdx.x & 63;
    const int m16 = meta[16];
    const int NT = m16 + (RCAP - SHOFF);   // valid rows (routed + shared)
    const int gap = SHOFF - m16;

    for (int t = gwid; t < NT; t += 4096) {
        const int r = (t < m16) ? t : t + gap;
        const char* src = (const char*)(hg + (size_t)r * FDIM);
        u32x4 P0 = ntld16(src + lane * 16);
        u32x4 P1 = ntld16(src + 1024 + lane * 16);
        u32x4 P2 = ntld16(src + 2048 + lane * 16);
        u32x4 P3 = ntld16(src + 3072 + lane * 16);
        float m = fmaxf(fmaxf(absmax8(P0), absmax8(P1)),
                        fmaxf(absmax8(P2), absmax8(P3)));
        m = fmaxf(wredmax(m), 1e-8f);
        if (lane == 0) sh[r] = m / 127.f;
        const float inv = 127.f / m;
        char* d = h8 + (size_t)r * FDIM;
        store8(d + lane * 8,        P0, inv);
        store8(d + 512 + lane * 8,  P1, inv);
        store8(d + 1024 + lane * 8, P2, inv);
        store8(d + 1536 + lane * 8, P3, inv);
    }
}

// ---------------- Combine ----------------
__global__ __launch_bounds__(256) void combine_kernel(
    const u16* __restrict__ yg, const float* __restrict__ top_w,
    const int* __restrict__ tok_rows, void* __restrict__ out_, const int* __restrict__ meta)
{
    const int t = blockIdx.x;
    const int r0 = tok_rows[2 * t], r1 = tok_rows[2 * t + 1];
    const float w0 = top_w[2 * t], w1 = top_w[2 * t + 1];
    const int d = threadIdx.x * 4;
    union { u32x2 v; u16 h[4]; } y0, y1, ys;
    y0.v = ntld8((const char*)(yg + (size_t)r0 * DDIM + d));
    y1.v = ntld8((const char*)(yg + (size_t)r1 * DDIM + d));
    ys.v = ntld8((const char*)(yg + (size_t)(SHOFF + t) * DDIM + d));
    float o0 = w0 * bf2f(y0.h[0]) + w1 * bf2f(y1.h[0]) + bf2f(ys.h[0]);
    float o1 = w0 * bf2f(y0.h[1]) + w1 * bf2f(y1.h[1]) + bf2f(ys.h[1]);
    float o2 = w0 * bf2f(y0.h[2]) + w1 * bf2f(y1.h[2]) + bf2f(ys.h[2]);
    float o3 = w0 * bf2f(y0.h[3]) + w1 * bf2f(y1.h[3]) + bf2f(ys.h[3]);
    if (!meta[30]) {
        union { u32x2 v; u16 h[4]; } o;
        o.h[0] = f2bf(o0); o.h[1] = f2bf(o1); o.h[2] = f2bf(o2); o.h[3] = f2bf(o3);
        ntst8((char*)((u16*)out_ + (size_t)t * DDIM + d), o.v);
    } else {
        float4 o; o.x = o0; o.y = o1; o.z = o2; o.w = o3;
        *(float4*)((float*)out_ + (size_t)t * DDIM + d) = o;
    }
}

extern "C" void kernel_launch(void* const* d_in, const int* in_sizes, int n_in,
                              void* d_out, int out_size, void* d_ws, size_t ws_size,
                              hipStream_t stream) {
    const void* x       = d_in[0];
    const void* rw      = d_in[1];
    const void* rb      = d_in[2];
    const void* w_up    = d_in[3];
    const void* w_down  = d_in[4];
    const void* sw_up   = d_in[5];
    const void* sw_down = d_in[6];

    const int T = in_sizes[0] / DDIM;  // 4096

    char* ws = (char*)d_ws;
    int*   meta     = (int*)ws;
    float* top_w    = (float*)(ws + 1024);
    int*   top_idx  = (int*)(ws + 1024 + 8 * T);
    int*   tok_rows = (int*)(ws + 1024 + 16 * T);
    size_t off = 131072;
    u16*  yg = (u16*)(ws + off);            // down output (bf16)
    char* xq = (char*)(ws + off);           // aliased: xq dead before yg written
    off += (size_t)RCAP * DDIM * 2;
    u16*  hg = (u16*)(ws + off);            // up output (bf16)
    off += (size_t)RCAP * FDIM * 2;
    char* h8 = (char*)(ws + off);
    off += (size_t)RCAP * FDIM;
    char* qup = (char*)(ws + off);
    off += (size_t)(NEXP + 1) * FDIM * DDIM;
    char* qdn = (char*)(ws + off);
    off += (size_t)(NEXP + 1) * DDIM * FDIM;
    float* sxa = (float*)(ws + off); off += (size_t)RCAP * 4;
    float* sh  = (float*)(ws + off); off += (size_t)RCAP * 4;
    float* su  = (float*)(ws + off); off += (size_t)(NEXP + 1) * FDIM * 4;
    float* sd  = (float*)(ws + off); off += (size_t)(NEXP + 1) * DDIM * 4;

    const int nrb = T / 16;  // 256 router blocks, placed first in the fused grid
    // K1: router + wq-up (1152 streaming blocks co-run with router)
    fused_rw_kernel<<<nrb + 1152, 256, 0, stream>>>(
        x, rw, rb, w_up, sw_up, top_w, top_idx, qup, su, nrb);
    // K2: rank (publishes meta incl. dtype flag)
    rank_kernel<<<1, 1024, 0, stream>>>((const u16*)x, top_idx, tok_rows, meta);
    // K3: gather + token quant
    gather_q_kernel<<<T, 128, 0, stream>>>(x, tok_rows, xq, sxa, meta);
    // K4: up-GEMM (SiLU fused) + wq-down co-run
    gemm_up_wqdn<<<NG_UP + 1152, 256, 0, stream>>>(
        xq, qup, sxa, su, hg, meta, w_down, sw_down, qdn, sd);
    // K5: h quantize
    hquant_kernel<<<1024, 256, 0, stream>>>(hg, h8, sh, meta);
    // K6: down-GEMM
    moe_gemm_i8<<<dim3(DDIM / 128, NRT), 256, 0, stream>>>(
        h8, qdn, sh, sd, yg, meta, DDIM, FDIM, 0);
    // K7: combine
    combine_kernel<<<T, 256, 0, stream>>>(yg, top_w, tok_rows, d_out, meta);
}